// Round 9
// baseline (438.228 us; speedup 1.0000x reference)
//
#include <hip/hip_runtime.h>
#include <hip/hip_bf16.h>

#define HD 128

typedef unsigned int u32;
typedef unsigned short u16;
typedef __attribute__((ext_vector_type(8))) short short8;   // 8 bf16 (4 VGPRs)
typedef __attribute__((ext_vector_type(4))) float f32x4;    // MFMA C/D

__device__ __forceinline__ float bf2f(u16 u) {
    return __uint_as_float(((u32)u) << 16);
}
__device__ __forceinline__ u16 f2bf(float f) {
    u32 u = __float_as_uint(f);
    u32 r = (u + 0x7fffu + ((u >> 16) & 1u)) >> 16;   // RNE
    return (u16)r;
}
// packed RNE f32x2 -> bf16x2 (v_cvt_pk_bf16_f32); lo -> low 16 bits
__device__ __forceinline__ u32 pk2bf(float lo, float hi) {
    __hip_bfloat162 h = __float22bfloat162_rn(make_float2(lo, hi));
    union { __hip_bfloat162 h; u32 u; } cv; cv.h = h;
    return cv.u;
}
__device__ __forceinline__ float ldf(const void* p, size_t i, bool f32m) {
    return f32m ? ((const float*)p)[i] : bf2f(((const u16*)p)[i]);
}
// XOR-swizzled halfword index into a 64x128 bf16 LDS tile (16B-block swizzle).
// All tile accesses are >=4-halfword aligned within an 8-halfword block, so
// vector widths survive; per-16-lane phase every access pattern is <=2-way.
__device__ __forceinline__ int swz(int row, int col) {
    return row * 128 + ((((col >> 3) ^ (row & 7)) << 3) | (col & 7));
}

// ---- dtype detector (parallel): f32 N(0,1) words have exp-field ~[110,131] ----
__global__ void detect_mode(const u32* __restrict__ x, int* __restrict__ mode) {
    __shared__ int cnt_s;
    if (threadIdx.x == 0) cnt_s = 0;
    __syncthreads();
    u32 e = (x[threadIdx.x] >> 23) & 0xFFu;
    if (e >= 90u && e < 170u) atomicAdd(&cnt_s, 1);
    __syncthreads();
    if (threadIdx.x == 0) mode[0] = (cnt_s >= 128) ? 1 : 0;
}

// ---- pack six 128x128 weight matrices into MFMA fragment order (bf16) ----
// out[((tile*4 + ks)*64 + lane)*8 + j] = W[ks*32 + (lane>>4)*8 + j][tile*16 + (lane&15)]
// serves as B-frag of W (z@W) AND as A-frag of W^T (W^T@z^T) — same bits.
__global__ void pack_w6(const void* __restrict__ W0, const void* __restrict__ W1,
                        const void* __restrict__ W2, const void* __restrict__ W3,
                        const void* __restrict__ W4, const void* __restrict__ W5,
                        u16* __restrict__ out, const int* __restrict__ gmode) {
    const bool f32m = gmode[0] != 0;
    int gid = blockIdx.x * 256 + threadIdx.x;
    if (gid >= 6 * 16384) return;
    int sel = gid >> 14, idx = gid & 16383;
    const void* W = sel == 0 ? W0 : sel == 1 ? W1 : sel == 2 ? W2 :
                    sel == 3 ? W3 : sel == 4 ? W4 : W5;
    int j = idx & 7, lane = (idx >> 3) & 63, ks = (idx >> 9) & 3, nt = idx >> 11;
    int k = ks * 32 + (lane >> 4) * 8 + j;
    int n = nt * 16 + (lane & 15);
    out[gid] = f2bf(ldf(W, (size_t)k * HD + n, f32m));
}

// ================= CSR build (once; graph shared by both layers) ===========
__global__ void cnt_count(const int* __restrict__ dst, int* __restrict__ cnt, int e) {
    int i = blockIdx.x * 256 + threadIdx.x;
    if (i < e) atomicAdd(&cnt[dst[i]], 1);
}

__global__ void scan_blocks(const int* __restrict__ cnt, int* __restrict__ rowptr,
                            int* __restrict__ bsum, int n) {
    __shared__ int s[256];
    int t = threadIdx.x, gid = blockIdx.x * 256 + t;
    int v = (gid < n) ? cnt[gid] : 0;
    s[t] = v; __syncthreads();
    #pragma unroll
    for (int off = 1; off < 256; off <<= 1) {
        int x = (t >= off) ? s[t - off] : 0;
        __syncthreads();
        s[t] += x;
        __syncthreads();
    }
    if (gid < n) rowptr[gid] = s[t] - v;
    if (t == 255) bsum[blockIdx.x] = s[255];
}

__global__ void scan_bsum(int* __restrict__ bsum, int nb) {
    __shared__ int s[1024];
    __shared__ int carry;
    int t = threadIdx.x;
    if (t == 0) carry = 0;
    __syncthreads();
    for (int base = 0; base < nb; base += 1024) {
        int i = base + t;
        int v = (i < nb) ? bsum[i] : 0;
        s[t] = v; __syncthreads();
        #pragma unroll
        for (int off = 1; off < 1024; off <<= 1) {
            int x = (t >= off) ? s[t - off] : 0;
            __syncthreads();
            s[t] += x;
            __syncthreads();
        }
        if (i < nb) bsum[i] = carry + s[t] - v;
        __syncthreads();
        if (t == 0) carry += s[1023];
        __syncthreads();
    }
}

__global__ void scan_add(int* __restrict__ rowptr, const int* __restrict__ bsum,
                         int n, int e) {
    int gid = blockIdx.x * 256 + threadIdx.x;
    if (gid < n) rowptr[gid] += bsum[blockIdx.x];
    else if (gid == n) rowptr[n] = e;
}

__global__ void csr_fill(const int* __restrict__ src, const int* __restrict__ dst,
                         const int* __restrict__ rowptr, int* __restrict__ cur,
                         int* __restrict__ cidx, int e) {
    int i = blockIdx.x * 256 + threadIdx.x;
    if (i >= e) return;
    int d = dst[i];
    int p = rowptr[d] + atomicAdd(&cur[d], 1);
    cidx[p] = src[i];
}

// ---- CSR gather-aggregate -> bf16 mean (invdeg pre-applied), no atomics ----
// one wave per dst node, 2 feats/lane; 4-deep load pipeline.
__global__ __launch_bounds__(256) void agg_gather(
    const void* __restrict__ h, const int* __restrict__ rowptr,
    const int* __restrict__ cidx, u16* __restrict__ aggb,
    const int* __restrict__ gmode, int use_mode, int n) {
    const bool f32m = use_mode && (gmode[0] != 0);
    int wid = (blockIdx.x * 256 + threadIdx.x) >> 6;
    int lane = threadIdx.x & 63;
    if (wid >= n) return;
    int s0 = rowptr[wid], s1 = rowptr[wid + 1];
    float a0 = 0.f, a1 = 0.f;
    int i = s0;
    if (f32m) {
        for (; i + 3 < s1; i += 4) {
            int sA = cidx[i], sB = cidx[i + 1], sC = cidx[i + 2], sD = cidx[i + 3];
            float2 vA = *(const float2*)((const float*)h + (size_t)sA * HD + lane * 2);
            float2 vB = *(const float2*)((const float*)h + (size_t)sB * HD + lane * 2);
            float2 vC = *(const float2*)((const float*)h + (size_t)sC * HD + lane * 2);
            float2 vD = *(const float2*)((const float*)h + (size_t)sD * HD + lane * 2);
            a0 += (vA.x + vB.x) + (vC.x + vD.x);
            a1 += (vA.y + vB.y) + (vC.y + vD.y);
        }
        for (; i < s1; i++) {
            float2 v = *(const float2*)((const float*)h + (size_t)cidx[i] * HD + lane * 2);
            a0 += v.x; a1 += v.y;
        }
    } else {
        for (; i + 3 < s1; i += 4) {
            int sA = cidx[i], sB = cidx[i + 1], sC = cidx[i + 2], sD = cidx[i + 3];
            u32 vA = *(const u32*)((const u16*)h + (size_t)sA * HD + lane * 2);
            u32 vB = *(const u32*)((const u16*)h + (size_t)sB * HD + lane * 2);
            u32 vC = *(const u32*)((const u16*)h + (size_t)sC * HD + lane * 2);
            u32 vD = *(const u32*)((const u16*)h + (size_t)sD * HD + lane * 2);
            a0 += (__uint_as_float(vA << 16) + __uint_as_float(vB << 16))
                + (__uint_as_float(vC << 16) + __uint_as_float(vD << 16));
            a1 += (__uint_as_float(vA & 0xffff0000u) + __uint_as_float(vB & 0xffff0000u))
                + (__uint_as_float(vC & 0xffff0000u) + __uint_as_float(vD & 0xffff0000u));
        }
        for (; i < s1; i++) {
            u32 v = *(const u32*)((const u16*)h + (size_t)cidx[i] * HD + lane * 2);
            a0 += __uint_as_float(v << 16);
            a1 += __uint_as_float(v & 0xffff0000u);
        }
    }
    float iv = 1.f / fmaxf((float)(s1 - s0), 1.f);
    *(u32*)&aggb[(size_t)wid * HD + lane * 2] = pk2bf(a0 * iv, a1 * iv);
}

// ---- MFMA SAGE layer, operand-swapped: D = Ws^T@zS^T + Wn^T@zN^T + b ----
template <bool RELU>
__global__ __launch_bounds__(256) void sage_mfma(
    const void* __restrict__ X, const u16* __restrict__ aggb,
    const u16* __restrict__ Wsp, const u16* __restrict__ Wnp,
    const void* __restrict__ bias, u16* __restrict__ hout,
    const int* __restrict__ gmode, int use_mode, int n) {
    __shared__ u16 zS[64 * 128];   // swizzled tiles, 16 KB each
    __shared__ u16 zN[64 * 128];
    u16* outh = zS;   // aliased after barrier

    const bool f32m = gmode[0] != 0;
    const bool inf32 = use_mode && f32m;
    const int t = threadIdx.x;
    const int n0 = blockIdx.x * 64;
    const int lane = t & 63;
    const int w = t >> 6;
    const int cl = lane & 15, quad = lane >> 4;

    // ---- stage both tiles ----
    #pragma unroll
    for (int i = 0; i < 8; i++) {
        int idx = t + i * 256;
        int e = idx >> 5, fg = (idx & 31) * 4;
        int node = n0 + e;
        u32 p0 = 0, p1 = 0, q0 = 0, q1 = 0;
        if (node < n) {
            if (inf32) {
                float4 v = *(const float4*)((const float*)X + (size_t)node * HD + fg);
                p0 = pk2bf(v.x, v.y); p1 = pk2bf(v.z, v.w);
            } else {
                uint2 v = *(const uint2*)((const u16*)X + (size_t)node * HD + fg);
                p0 = v.x; p1 = v.y;
            }
            uint2 a = *(const uint2*)&aggb[(size_t)node * HD + fg];
            q0 = a.x; q1 = a.y;
        }
        int sa = swz(e, fg);
        *(uint2*)&zS[sa] = make_uint2(p0, p1);
        *(uint2*)&zN[sa] = make_uint2(q0, q1);
    }
    __syncthreads();

    // ---- MFMA (swapped): acc[ft][et], feat = w*32+ft*16+quad*4+r, node = et*16+cl
    f32x4 acc[2][4];
    #pragma unroll
    for (int ft = 0; ft < 2; ft++) {
        int f0 = w * 32 + ft * 16 + quad * 4;
        f32x4 bv;
        bv[0] = ldf(bias, f0 + 0, f32m);
        bv[1] = ldf(bias, f0 + 1, f32m);
        bv[2] = ldf(bias, f0 + 2, f32m);
        bv[3] = ldf(bias, f0 + 3, f32m);
        #pragma unroll
        for (int et = 0; et < 4; et++) acc[ft][et] = bv;
    }
    #pragma unroll
    for (int ks = 0; ks < 4; ks++) {
        short8 aS[2], aN[2], bS[4], bN[4];
        #pragma unroll
        for (int ft = 0; ft < 2; ft++) {
            aS[ft] = ((const short8*)Wsp)[((w * 2 + ft) * 4 + ks) * 64 + lane];
            aN[ft] = ((const short8*)Wnp)[((w * 2 + ft) * 4 + ks) * 64 + lane];
        }
        #pragma unroll
        for (int et = 0; et < 4; et++) {
            int sa = swz(et * 16 + cl, ks * 32 + quad * 8);
            bS[et] = *(const short8*)&zS[sa];
            bN[et] = *(const short8*)&zN[sa];
        }
        #pragma unroll
        for (int ft = 0; ft < 2; ft++)
            #pragma unroll
            for (int et = 0; et < 4; et++) {
                acc[ft][et] = __builtin_amdgcn_mfma_f32_16x16x32_bf16(
                    aS[ft], bS[et], acc[ft][et], 0, 0, 0);
                acc[ft][et] = __builtin_amdgcn_mfma_f32_16x16x32_bf16(
                    aN[ft], bN[et], acc[ft][et], 0, 0, 0);
            }
    }
    __syncthreads();   // all waves done reading zS/zN before aliasing as output

    // ---- epilogue: packed b64 swizzled LDS writes, then coalesced global copy ----
    #pragma unroll
    for (int ft = 0; ft < 2; ft++) {
        int f0 = w * 32 + ft * 16 + quad * 4;
        #pragma unroll
        for (int et = 0; et < 4; et++) {
            f32x4 v = acc[ft][et];
            float v0 = RELU ? fmaxf(v[0], 0.f) : v[0];
            float v1 = RELU ? fmaxf(v[1], 0.f) : v[1];
            float v2 = RELU ? fmaxf(v[2], 0.f) : v[2];
            float v3 = RELU ? fmaxf(v[3], 0.f) : v[3];
            *(uint2*)&outh[swz(et * 16 + cl, f0)] =
                make_uint2(pk2bf(v0, v1), pk2bf(v2, v3));
        }
    }
    __syncthreads();
    #pragma unroll
    for (int i = 0; i < 8; i++) {
        int idx = t + i * 256;
        int e = idx >> 5, fg = (idx & 31) * 4;
        int node = n0 + e;
        if (node < n)
            *(uint2*)&hout[(size_t)node * HD + fg] = *(const uint2*)&outh[swz(e, fg)];
    }
}

// ---- 64x128x128 MFMA GEMM stage, swapped, relu, bf16 out (swizzled LDS) ----
__device__ __forceinline__ void gemm128(
    const u16* zin, u16* zout, const u16* __restrict__ Wp,
    const void* __restrict__ bias, bool f32m, int w, int lane) {
    const int cl = lane & 15, quad = lane >> 4;
    f32x4 acc[2][4];   // [ft][et]
    #pragma unroll
    for (int ft = 0; ft < 2; ft++) {
        int f0 = w * 32 + ft * 16 + quad * 4;
        f32x4 bv;
        bv[0] = ldf(bias, f0 + 0, f32m);
        bv[1] = ldf(bias, f0 + 1, f32m);
        bv[2] = ldf(bias, f0 + 2, f32m);
        bv[3] = ldf(bias, f0 + 3, f32m);
        #pragma unroll
        for (int et = 0; et < 4; et++) acc[ft][et] = bv;
    }
    #pragma unroll
    for (int ks = 0; ks < 4; ks++) {
        short8 a[2], b[4];
        #pragma unroll
        for (int ft = 0; ft < 2; ft++)
            a[ft] = ((const short8*)Wp)[((w * 2 + ft) * 4 + ks) * 64 + lane];
        #pragma unroll
        for (int et = 0; et < 4; et++)
            b[et] = *(const short8*)&zin[swz(et * 16 + cl, ks * 32 + quad * 8)];
        #pragma unroll
        for (int ft = 0; ft < 2; ft++)
            #pragma unroll
            for (int et = 0; et < 4; et++)
                acc[ft][et] = __builtin_amdgcn_mfma_f32_16x16x32_bf16(
                    a[ft], b[et], acc[ft][et], 0, 0, 0);
    }
    #pragma unroll
    for (int ft = 0; ft < 2; ft++) {
        int f0 = w * 32 + ft * 16 + quad * 4;
        #pragma unroll
        for (int et = 0; et < 4; et++) {
            f32x4 v = acc[ft][et];
            *(uint2*)&zout[swz(et * 16 + cl, f0)] = make_uint2(
                pk2bf(fmaxf(v[0], 0.f), fmaxf(v[1], 0.f)),
                pk2bf(fmaxf(v[2], 0.f), fmaxf(v[3], 0.f)));
        }
    }
}

// ---- MFMA edge decoder, pos+neg fused; gemm2 + W3-GEMV fully in registers ----
__global__ __launch_bounds__(256) void edge_decode_mfma(
    const u16* __restrict__ h,
    const int* __restrict__ psrc, const int* __restrict__ pdst, int ep, int PB,
    const int* __restrict__ nsrc, const int* __restrict__ ndst, int en,
    const u16* __restrict__ W1p, const void* __restrict__ b1,
    const u16* __restrict__ W2p, const void* __restrict__ b2,
    const void* __restrict__ W3, const void* __restrict__ b3,
    void* __restrict__ out, const int* __restrict__ gmode) {
    __shared__ u16 zA[64 * 128];
    __shared__ u16 zB[64 * 128];
    __shared__ float psum[256];
    const bool f32m = gmode[0] != 0;
    const int t = threadIdx.x;
    const int b = blockIdx.x;
    const int* esrc; const int* edst; int e0, obase, ne;
    if (b < PB) { esrc = psrc; edst = pdst; e0 = b * 64;        obase = 0;  ne = ep; }
    else        { esrc = nsrc; edst = ndst; e0 = (b - PB) * 64; obase = ep; ne = en; }
    const int lane = t & 63;
    const int w = t >> 6;
    const int cl = lane & 15, quad = lane >> 4;

    // ---- stage z0 = bf16(h[s]*h[d]) ----
    #pragma unroll
    for (int i = 0; i < 8; i++) {
        int idx = t + i * 256;
        int e = idx >> 5, fg = (idx & 31) * 4;
        int eg = e0 + e;
        u32 p0 = 0, p1 = 0;
        if (eg < ne) {
            int s = esrc[eg], d = edst[eg];
            uint2 a = *(const uint2*)(h + (size_t)s * HD + fg);
            uint2 b2v = *(const uint2*)(h + (size_t)d * HD + fg);
            float x0 = __uint_as_float(a.x << 16)         * __uint_as_float(b2v.x << 16);
            float x1 = __uint_as_float(a.x & 0xffff0000u) * __uint_as_float(b2v.x & 0xffff0000u);
            float x2 = __uint_as_float(a.y << 16)         * __uint_as_float(b2v.y << 16);
            float x3 = __uint_as_float(a.y & 0xffff0000u) * __uint_as_float(b2v.y & 0xffff0000u);
            p0 = pk2bf(x0, x1);
            p1 = pk2bf(x2, x3);
        }
        *(uint2*)&zA[swz(e, fg)] = make_uint2(p0, p1);
    }
    __syncthreads();

    gemm128(zA, zB, W1p, b1, f32m, w, lane);   // z1 = relu(z0@W1+b1) -> zB
    __syncthreads();

    // ---- gemm2 in registers + W3 dot ----
    f32x4 acc[2][4];
    #pragma unroll
    for (int ft = 0; ft < 2; ft++) {
        int f0 = w * 32 + ft * 16 + quad * 4;
        f32x4 bv;
        bv[0] = ldf(b2, f0 + 0, f32m);
        bv[1] = ldf(b2, f0 + 1, f32m);
        bv[2] = ldf(b2, f0 + 2, f32m);
        bv[3] = ldf(b2, f0 + 3, f32m);
        #pragma unroll
        for (int et = 0; et < 4; et++) acc[ft][et] = bv;
    }
    #pragma unroll
    for (int ks = 0; ks < 4; ks++) {
        short8 a[2], bb[4];
        #pragma unroll
        for (int ft = 0; ft < 2; ft++)
            a[ft] = ((const short8*)W2p)[((w * 2 + ft) * 4 + ks) * 64 + lane];
        #pragma unroll
        for (int et = 0; et < 4; et++)
            bb[et] = *(const short8*)&zB[swz(et * 16 + cl, ks * 32 + quad * 8)];
        #pragma unroll
        for (int ft = 0; ft < 2; ft++)
            #pragma unroll
            for (int et = 0; et < 4; et++)
                acc[ft][et] = __builtin_amdgcn_mfma_f32_16x16x32_bf16(
                    a[ft], bb[et], acc[ft][et], 0, 0, 0);
    }
    // per-lane partial dot of relu(z2) with W3 over this lane's 8 feats
    float p[4] = {0.f, 0.f, 0.f, 0.f};
    #pragma unroll
    for (int ft = 0; ft < 2; ft++) {
        int f0 = w * 32 + ft * 16 + quad * 4;
        float w3v0 = ldf(W3, f0 + 0, f32m);
        float w3v1 = ldf(W3, f0 + 1, f32m);
        float w3v2 = ldf(W3, f0 + 2, f32m);
        float w3v3 = ldf(W3, f0 + 3, f32m);
        #pragma unroll
        for (int et = 0; et < 4; et++) {
            f32x4 v = acc[ft][et];
            p[et] = fmaf(fmaxf(v[0], 0.f), w3v0, p[et]);
            p[et] = fmaf(fmaxf(v[1], 0.f), w3v1, p[et]);
            p[et] = fmaf(fmaxf(v[2], 0.f), w3v2, p[et]);
            p[et] = fmaf(fmaxf(v[3], 0.f), w3v3, p[et]);
        }
    }
    // reduce over quads (lanes cl, cl+16, cl+32, cl+48)
    #pragma unroll
    for (int et = 0; et < 4; et++) {
        p[et] += __shfl_xor(p[et], 16);
        p[et] += __shfl_xor(p[et], 32);
    }
    if (lane < 16) {
        #pragma unroll
        for (int et = 0; et < 4; et++)
            psum[w * 64 + et * 16 + lane] = p[et];
    }
    __syncthreads();
    if (t < 64) {
        int eg = e0 + t;
        if (eg < ne) {
            float sum = ldf(b3, 0, f32m) + (psum[t] + psum[64 + t])
                      + (psum[128 + t] + psum[192 + t]);
            if (f32m) ((float*)out)[obase + eg] = sum;
            else      ((u16*)out)[obase + eg]   = f2bf(sum);
        }
    }
}

extern "C" void kernel_launch(void* const* d_in, const int* in_sizes, int n_in,
                              void* d_out, int out_size, void* d_ws, size_t ws_size,
                              hipStream_t stream) {
    const void* x      = d_in[0];
    const int* src     = (const int*)d_in[1];
    const int* dst     = (const int*)d_in[2];
    const int* pos_src = (const int*)d_in[3];
    const int* pos_dst = (const int*)d_in[4];
    const int* neg_src = (const int*)d_in[5];
    const int* neg_dst = (const int*)d_in[6];
    const void* Ws0 = d_in[7];
    const void* Wn0 = d_in[8];
    const void* b0  = d_in[9];
    const void* Ws1 = d_in[10];
    const void* Wn1 = d_in[11];
    const void* b1  = d_in[12];
    const void* dW1 = d_in[13];
    const void* db1 = d_in[14];
    const void* dW2 = d_in[15];
    const void* db2 = d_in[16];
    const void* dW3 = d_in[17];
    const void* db3 = d_in[18];

    const int n  = in_sizes[0] / HD;
    const int e  = in_sizes[1];
    const int ep = in_sizes[3];
    const int en = in_sizes[5];
    const int NB = (n + 255) / 256;
    const int PB = (ep + 63) / 64, NDB = (en + 63) / 64;

    // ws: aggb/h2[n*HD] u16 | h1[n*HD] u16 | mode | rowptr | cnt | cidx | bsum | packed W x6
    char* base = (char*)d_ws;
    u16* aggb = (u16*)d_ws;              // doubles as h2 (block-private rows)
    u16* h1   = aggb + (size_t)n * HD;
    size_t off = (size_t)n * HD * 4;     // two u16 planes
    int* mode = (int*)(base + off);      off += 16;
    int* rowptr = (int*)(base + off);    off += (size_t)(n + 1) * 4; off = (off + 15) & ~(size_t)15;
    int* cnt = (int*)(base + off);       off += (size_t)n * 4;       off = (off + 15) & ~(size_t)15;
    int* cidx = (int*)(base + off);      off += (size_t)e * 4;       off = (off + 15) & ~(size_t)15;
    int* bsum = (int*)(base + off);      off += (size_t)NB * 4;      off = (off + 15) & ~(size_t)15;
    u16* Wpk  = (u16*)(base + off);      // order: dW1, dW2, Ws0, Wn0, Ws1, Wn1
    u16* W1p  = Wpk;
    u16* W2p  = Wpk + 16384;
    u16* Ws0p = Wpk + 2 * 16384;
    u16* Wn0p = Wpk + 3 * 16384;
    u16* Ws1p = Wpk + 4 * 16384;
    u16* Wn1p = Wpk + 5 * 16384;

    detect_mode<<<dim3(1), dim3(256), 0, stream>>>((const u32*)x, mode);

    // ---- CSR build (once) ----
    hipMemsetAsync(cnt, 0, (size_t)n * 4, stream);
    cnt_count<<<dim3((e + 255) / 256), dim3(256), 0, stream>>>(dst, cnt, e);
    scan_blocks<<<dim3(NB), dim3(256), 0, stream>>>(cnt, rowptr, bsum, n);
    scan_bsum<<<dim3(1), dim3(1024), 0, stream>>>(bsum, NB);
    scan_add<<<dim3((n + 256) / 256), dim3(256), 0, stream>>>(rowptr, bsum, n, e);
    hipMemsetAsync(cnt, 0, (size_t)n * 4, stream);   // reuse as cursor
    csr_fill<<<dim3((e + 255) / 256), dim3(256), 0, stream>>>(src, dst, rowptr, cnt, cidx, e);

    pack_w6<<<dim3(384), dim3(256), 0, stream>>>(dW1, dW2, Ws0, Wn0, Ws1, Wn1, Wpk, mode);

    // ---- layer 0: h1 = relu(x@Ws0 + mean@Wn0 + b0) ----
    agg_gather<<<dim3((n * 64 + 255) / 256), dim3(256), 0, stream>>>(
        x, rowptr, cidx, aggb, mode, 1, n);
    sage_mfma<true><<<dim3((n + 63) / 64), dim3(256), 0, stream>>>(
        x, aggb, Ws0p, Wn0p, b0, h1, mode, 1, n);

    // ---- layer 1: h2 = h1@Ws1 + mean(h1)@Wn1 + b1  (h2 aliases aggb) ----
    agg_gather<<<dim3((n * 64 + 255) / 256), dim3(256), 0, stream>>>(
        h1, rowptr, cidx, aggb, mode, 0, n);
    sage_mfma<false><<<dim3((n + 63) / 64), dim3(256), 0, stream>>>(
        h1, aggb, Ws1p, Wn1p, b1, aggb /*h2 in-place*/, mode, 0, n);

    // ---- fused pos+neg decoder on h2 (bf16) ----
    edge_decode_mfma<<<dim3(PB + NDB), dim3(256), 0, stream>>>(
        aggb, pos_src, pos_dst, ep, PB, neg_src, neg_dst, en,
        W1p, db1, W2p, db2, dW3, db3, d_out, mode);
}

// Round 10
// 377.366 us; speedup vs baseline: 1.1613x; 1.1613x over previous
//
#include <hip/hip_runtime.h>
#include <hip/hip_bf16.h>

#define HD 128

typedef unsigned int u32;
typedef unsigned short u16;
typedef __attribute__((ext_vector_type(8))) short short8;   // 8 bf16 (4 VGPRs)
typedef __attribute__((ext_vector_type(4))) float f32x4;    // MFMA C/D

__device__ __forceinline__ float bf2f(u16 u) {
    return __uint_as_float(((u32)u) << 16);
}
__device__ __forceinline__ u16 f2bf(float f) {
    u32 u = __float_as_uint(f);
    u32 r = (u + 0x7fffu + ((u >> 16) & 1u)) >> 16;   // RNE
    return (u16)r;
}
// packed RNE f32x2 -> bf16x2 (v_cvt_pk_bf16_f32); lo -> low 16 bits
__device__ __forceinline__ u32 pk2bf(float lo, float hi) {
    __hip_bfloat162 h = __float22bfloat162_rn(make_float2(lo, hi));
    union { __hip_bfloat162 h; u32 u; } cv; cv.h = h;
    return cv.u;
}
// packed bf16x2 multiply (RNE — bit-identical to f32-mul + RNE-to-bf16)
__device__ __forceinline__ u32 hmul2(u32 a, u32 b) {
    union { u32 u; __hip_bfloat162 h; } x, y, r;
    x.u = a; y.u = b;
    r.h = __hmul2(x.h, y.h);
    return r.u;
}
__device__ __forceinline__ float ldf(const void* p, size_t i, bool f32m) {
    return f32m ? ((const float*)p)[i] : bf2f(((const u16*)p)[i]);
}
// XOR-swizzled halfword index into a 64x128 bf16 LDS tile (16B-block swizzle).
__device__ __forceinline__ int swz(int row, int col) {
    return row * 128 + ((((col >> 3) ^ (row & 7)) << 3) | (col & 7));
}

// ---- dtype detector (parallel): f32 N(0,1) words have exp-field ~[110,131] ----
__global__ void detect_mode(const u32* __restrict__ x, int* __restrict__ mode) {
    __shared__ int cnt_s;
    if (threadIdx.x == 0) cnt_s = 0;
    __syncthreads();
    u32 e = (x[threadIdx.x] >> 23) & 0xFFu;
    if (e >= 90u && e < 170u) atomicAdd(&cnt_s, 1);
    __syncthreads();
    if (threadIdx.x == 0) mode[0] = (cnt_s >= 128) ? 1 : 0;
}

// ---- pack six 128x128 weight matrices into MFMA fragment order (bf16) ----
__global__ void pack_w6(const void* __restrict__ W0, const void* __restrict__ W1,
                        const void* __restrict__ W2, const void* __restrict__ W3,
                        const void* __restrict__ W4, const void* __restrict__ W5,
                        u16* __restrict__ out, const int* __restrict__ gmode) {
    const bool f32m = gmode[0] != 0;
    int gid = blockIdx.x * 256 + threadIdx.x;
    if (gid >= 6 * 16384) return;
    int sel = gid >> 14, idx = gid & 16383;
    const void* W = sel == 0 ? W0 : sel == 1 ? W1 : sel == 2 ? W2 :
                    sel == 3 ? W3 : sel == 4 ? W4 : W5;
    int j = idx & 7, lane = (idx >> 3) & 63, ks = (idx >> 9) & 3, nt = idx >> 11;
    int k = ks * 32 + (lane >> 4) * 8 + j;
    int n = nt * 16 + (lane & 15);
    out[gid] = f2bf(ldf(W, (size_t)k * HD + n, f32m));
}

// ================= CSR build (once; graph shared by both layers) ===========
__global__ void cnt_count(const int* __restrict__ dst, int* __restrict__ cnt, int e) {
    int i = blockIdx.x * 256 + threadIdx.x;
    if (i < e) atomicAdd(&cnt[dst[i]], 1);
}

__global__ void scan_blocks(const int* __restrict__ cnt, int* __restrict__ rowptr,
                            int* __restrict__ bsum, int n) {
    __shared__ int s[256];
    int t = threadIdx.x, gid = blockIdx.x * 256 + t;
    int v = (gid < n) ? cnt[gid] : 0;
    s[t] = v; __syncthreads();
    #pragma unroll
    for (int off = 1; off < 256; off <<= 1) {
        int x = (t >= off) ? s[t - off] : 0;
        __syncthreads();
        s[t] += x;
        __syncthreads();
    }
    if (gid < n) rowptr[gid] = s[t] - v;
    if (t == 255) bsum[blockIdx.x] = s[255];
}

__global__ void scan_bsum(int* __restrict__ bsum, int nb) {
    __shared__ int s[1024];
    __shared__ int carry;
    int t = threadIdx.x;
    if (t == 0) carry = 0;
    __syncthreads();
    for (int base = 0; base < nb; base += 1024) {
        int i = base + t;
        int v = (i < nb) ? bsum[i] : 0;
        s[t] = v; __syncthreads();
        #pragma unroll
        for (int off = 1; off < 1024; off <<= 1) {
            int x = (t >= off) ? s[t - off] : 0;
            __syncthreads();
            s[t] += x;
            __syncthreads();
        }
        if (i < nb) bsum[i] = carry + s[t] - v;
        __syncthreads();
        if (t == 0) carry += s[1023];
        __syncthreads();
    }
}

__global__ void scan_add(int* __restrict__ rowptr, const int* __restrict__ bsum,
                         int n, int e) {
    int gid = blockIdx.x * 256 + threadIdx.x;
    if (gid < n) rowptr[gid] += bsum[blockIdx.x];
    else if (gid == n) rowptr[n] = e;
}

__global__ void csr_fill(const int* __restrict__ src, const int* __restrict__ dst,
                         const int* __restrict__ rowptr, int* __restrict__ cur,
                         int* __restrict__ cidx, int e) {
    int i = blockIdx.x * 256 + threadIdx.x;
    if (i >= e) return;
    int d = dst[i];
    int p = rowptr[d] + atomicAdd(&cur[d], 1);
    cidx[p] = src[i];
}

// ---- CSR gather-aggregate -> bf16 mean, no atomics ----
// one wave per dst node; 16-lane group g loads a full 256-B row (16B/lane),
// neighbors strided by 4 across groups; f32 accumulate; shfl-xor reduce.
__global__ __launch_bounds__(256) void agg_gather(
    const void* __restrict__ h, const int* __restrict__ rowptr,
    const int* __restrict__ cidx, u16* __restrict__ aggb,
    const int* __restrict__ gmode, int use_mode, int n) {
    const bool f32m = use_mode && (gmode[0] != 0);
    int wid = (blockIdx.x * 256 + threadIdx.x) >> 6;
    int lane = threadIdx.x & 63;
    if (wid >= n) return;
    int l16 = lane & 15, g = lane >> 4;
    int s0 = rowptr[wid], s1 = rowptr[wid + 1];
    float acc[8] = {0.f, 0.f, 0.f, 0.f, 0.f, 0.f, 0.f, 0.f};
    for (int i = s0 + g; i < s1; i += 4) {
        int s = cidx[i];
        if (f32m) {
            const float* p = (const float*)h + (size_t)s * HD + l16 * 8;
            float4 a = *(const float4*)p, b = *(const float4*)(p + 4);
            acc[0] += a.x; acc[1] += a.y; acc[2] += a.z; acc[3] += a.w;
            acc[4] += b.x; acc[5] += b.y; acc[6] += b.z; acc[7] += b.w;
        } else {
            uint4 v = *(const uint4*)((const u16*)h + (size_t)s * HD + l16 * 8);
            acc[0] += __uint_as_float(v.x << 16); acc[1] += __uint_as_float(v.x & 0xffff0000u);
            acc[2] += __uint_as_float(v.y << 16); acc[3] += __uint_as_float(v.y & 0xffff0000u);
            acc[4] += __uint_as_float(v.z << 16); acc[5] += __uint_as_float(v.z & 0xffff0000u);
            acc[6] += __uint_as_float(v.w << 16); acc[7] += __uint_as_float(v.w & 0xffff0000u);
        }
    }
    #pragma unroll
    for (int k = 0; k < 8; k++) {
        acc[k] += __shfl_xor(acc[k], 16);
        acc[k] += __shfl_xor(acc[k], 32);
    }
    if (g == 0) {
        float iv = 1.f / fmaxf((float)(s1 - s0), 1.f);
        uint4 o;
        o.x = pk2bf(acc[0] * iv, acc[1] * iv);
        o.y = pk2bf(acc[2] * iv, acc[3] * iv);
        o.z = pk2bf(acc[4] * iv, acc[5] * iv);
        o.w = pk2bf(acc[6] * iv, acc[7] * iv);
        *(uint4*)&aggb[(size_t)wid * HD + l16 * 8] = o;
    }
}

// ---- MFMA SAGE layer, operand-swapped: D = Ws^T@zS^T + Wn^T@zN^T + b ----
template <bool RELU>
__global__ __launch_bounds__(256) void sage_mfma(
    const void* __restrict__ X, const u16* __restrict__ aggb,
    const u16* __restrict__ Wsp, const u16* __restrict__ Wnp,
    const void* __restrict__ bias, u16* __restrict__ hout,
    const int* __restrict__ gmode, int use_mode, int n) {
    __shared__ u16 zS[64 * 128];   // swizzled tiles, 16 KB each
    __shared__ u16 zN[64 * 128];
    u16* outh = zS;   // aliased after barrier

    const bool f32m = gmode[0] != 0;
    const bool inf32 = use_mode && f32m;
    const int t = threadIdx.x;
    const int n0 = blockIdx.x * 64;
    const int lane = t & 63;
    const int w = t >> 6;
    const int cl = lane & 15, quad = lane >> 4;

    // ---- stage both tiles: 16 B/lane segments ----
    #pragma unroll
    for (int i = 0; i < 4; i++) {
        int idx = t + i * 256;          // 1024 slots = 64 rows x 16 segs
        int e = idx >> 4, sg = (idx & 15) * 8;
        int node = n0 + e;
        uint4 p = make_uint4(0, 0, 0, 0), q = make_uint4(0, 0, 0, 0);
        if (node < n) {
            if (inf32) {
                const float* xp = (const float*)X + (size_t)node * HD + sg;
                float4 v0 = *(const float4*)xp, v1 = *(const float4*)(xp + 4);
                p.x = pk2bf(v0.x, v0.y); p.y = pk2bf(v0.z, v0.w);
                p.z = pk2bf(v1.x, v1.y); p.w = pk2bf(v1.z, v1.w);
            } else {
                p = *(const uint4*)((const u16*)X + (size_t)node * HD + sg);
            }
            q = *(const uint4*)&aggb[(size_t)node * HD + sg];
        }
        int sa = swz(e, sg);
        *(uint4*)&zS[sa] = p;
        *(uint4*)&zN[sa] = q;
    }
    __syncthreads();

    // ---- MFMA (swapped): acc[ft][et], feat = w*32+ft*16+quad*4+r, node = et*16+cl
    f32x4 acc[2][4];
    #pragma unroll
    for (int ft = 0; ft < 2; ft++) {
        int f0 = w * 32 + ft * 16 + quad * 4;
        f32x4 bv;
        bv[0] = ldf(bias, f0 + 0, f32m);
        bv[1] = ldf(bias, f0 + 1, f32m);
        bv[2] = ldf(bias, f0 + 2, f32m);
        bv[3] = ldf(bias, f0 + 3, f32m);
        #pragma unroll
        for (int et = 0; et < 4; et++) acc[ft][et] = bv;
    }
    #pragma unroll
    for (int ks = 0; ks < 4; ks++) {
        short8 aS[2], aN[2], bS[4], bN[4];
        #pragma unroll
        for (int ft = 0; ft < 2; ft++) {
            aS[ft] = ((const short8*)Wsp)[((w * 2 + ft) * 4 + ks) * 64 + lane];
            aN[ft] = ((const short8*)Wnp)[((w * 2 + ft) * 4 + ks) * 64 + lane];
        }
        #pragma unroll
        for (int et = 0; et < 4; et++) {
            int sa = swz(et * 16 + cl, ks * 32 + quad * 8);
            bS[et] = *(const short8*)&zS[sa];
            bN[et] = *(const short8*)&zN[sa];
        }
        #pragma unroll
        for (int ft = 0; ft < 2; ft++)
            #pragma unroll
            for (int et = 0; et < 4; et++) {
                acc[ft][et] = __builtin_amdgcn_mfma_f32_16x16x32_bf16(
                    aS[ft], bS[et], acc[ft][et], 0, 0, 0);
                acc[ft][et] = __builtin_amdgcn_mfma_f32_16x16x32_bf16(
                    aN[ft], bN[et], acc[ft][et], 0, 0, 0);
            }
    }
    __syncthreads();   // all waves done reading zS/zN before aliasing as output

    // ---- epilogue: packed b64 swizzled LDS writes, then coalesced global copy ----
    #pragma unroll
    for (int ft = 0; ft < 2; ft++) {
        int f0 = w * 32 + ft * 16 + quad * 4;
        #pragma unroll
        for (int et = 0; et < 4; et++) {
            f32x4 v = acc[ft][et];
            float v0 = RELU ? fmaxf(v[0], 0.f) : v[0];
            float v1 = RELU ? fmaxf(v[1], 0.f) : v[1];
            float v2 = RELU ? fmaxf(v[2], 0.f) : v[2];
            float v3 = RELU ? fmaxf(v[3], 0.f) : v[3];
            *(uint2*)&outh[swz(et * 16 + cl, f0)] =
                make_uint2(pk2bf(v0, v1), pk2bf(v2, v3));
        }
    }
    __syncthreads();
    #pragma unroll
    for (int i = 0; i < 4; i++) {
        int idx = t + i * 256;
        int e = idx >> 4, sg = (idx & 15) * 8;
        int node = n0 + e;
        if (node < n)
            *(uint4*)&hout[(size_t)node * HD + sg] = *(const uint4*)&outh[swz(e, sg)];
    }
}

// ---- 64x128x128 MFMA GEMM stage, swapped, relu, bf16 out (swizzled LDS) ----
__device__ __forceinline__ void gemm128(
    const u16* zin, u16* zout, const u16* __restrict__ Wp,
    const void* __restrict__ bias, bool f32m, int w, int lane) {
    const int cl = lane & 15, quad = lane >> 4;
    f32x4 acc[2][4];   // [ft][et]
    #pragma unroll
    for (int ft = 0; ft < 2; ft++) {
        int f0 = w * 32 + ft * 16 + quad * 4;
        f32x4 bv;
        bv[0] = ldf(bias, f0 + 0, f32m);
        bv[1] = ldf(bias, f0 + 1, f32m);
        bv[2] = ldf(bias, f0 + 2, f32m);
        bv[3] = ldf(bias, f0 + 3, f32m);
        #pragma unroll
        for (int et = 0; et < 4; et++) acc[ft][et] = bv;
    }
    #pragma unroll
    for (int ks = 0; ks < 4; ks++) {
        short8 a[2], b[4];
        #pragma unroll
        for (int ft = 0; ft < 2; ft++)
            a[ft] = ((const short8*)Wp)[((w * 2 + ft) * 4 + ks) * 64 + lane];
        #pragma unroll
        for (int et = 0; et < 4; et++)
            b[et] = *(const short8*)&zin[swz(et * 16 + cl, ks * 32 + quad * 8)];
        #pragma unroll
        for (int ft = 0; ft < 2; ft++)
            #pragma unroll
            for (int et = 0; et < 4; et++)
                acc[ft][et] = __builtin_amdgcn_mfma_f32_16x16x32_bf16(
                    a[ft], b[et], acc[ft][et], 0, 0, 0);
    }
    #pragma unroll
    for (int ft = 0; ft < 2; ft++) {
        int f0 = w * 32 + ft * 16 + quad * 4;
        #pragma unroll
        for (int et = 0; et < 4; et++) {
            f32x4 v = acc[ft][et];
            *(uint2*)&zout[swz(et * 16 + cl, f0)] = make_uint2(
                pk2bf(fmaxf(v[0], 0.f), fmaxf(v[1], 0.f)),
                pk2bf(fmaxf(v[2], 0.f), fmaxf(v[3], 0.f)));
        }
    }
}

// ---- MFMA edge decoder, pos+neg fused; gemm2 + W3-GEMV fully in registers ----
__global__ __launch_bounds__(256) void edge_decode_mfma(
    const u16* __restrict__ h,
    const int* __restrict__ psrc, const int* __restrict__ pdst, int ep, int PB,
    const int* __restrict__ nsrc, const int* __restrict__ ndst, int en,
    const u16* __restrict__ W1p, const void* __restrict__ b1,
    const u16* __restrict__ W2p, const void* __restrict__ b2,
    const void* __restrict__ W3, const void* __restrict__ b3,
    void* __restrict__ out, const int* __restrict__ gmode) {
    __shared__ u16 zA[64 * 128];
    __shared__ u16 zB[64 * 128];
    __shared__ float psum[256];
    const bool f32m = gmode[0] != 0;
    const int t = threadIdx.x;
    const int b = blockIdx.x;
    const int* esrc; const int* edst; int e0, obase, ne;
    if (b < PB) { esrc = psrc; edst = pdst; e0 = b * 64;        obase = 0;  ne = ep; }
    else        { esrc = nsrc; edst = ndst; e0 = (b - PB) * 64; obase = ep; ne = en; }
    const int lane = t & 63;
    const int w = t >> 6;
    const int cl = lane & 15, quad = lane >> 4;

    // ---- stage z0 = bf16(h[s]*h[d]): 16 B/lane, packed bf16 mul ----
    #pragma unroll
    for (int i = 0; i < 4; i++) {
        int idx = t + i * 256;          // 1024 slots = 64 edges x 16 segs
        int e = idx >> 4, sg = (idx & 15) * 8;
        int eg = e0 + e;
        uint4 z = make_uint4(0, 0, 0, 0);
        if (eg < ne) {
            int s = esrc[eg], d = edst[eg];
            uint4 a  = *(const uint4*)(h + (size_t)s * HD + sg);
            uint4 bv = *(const uint4*)(h + (size_t)d * HD + sg);
            z.x = hmul2(a.x, bv.x); z.y = hmul2(a.y, bv.y);
            z.z = hmul2(a.z, bv.z); z.w = hmul2(a.w, bv.w);
        }
        *(uint4*)&zA[swz(e, sg)] = z;
    }
    __syncthreads();

    gemm128(zA, zB, W1p, b1, f32m, w, lane);   // z1 = relu(z0@W1+b1) -> zB
    __syncthreads();

    // ---- gemm2 in registers + W3 dot ----
    f32x4 acc[2][4];
    #pragma unroll
    for (int ft = 0; ft < 2; ft++) {
        int f0 = w * 32 + ft * 16 + quad * 4;
        f32x4 bv;
        bv[0] = ldf(b2, f0 + 0, f32m);
        bv[1] = ldf(b2, f0 + 1, f32m);
        bv[2] = ldf(b2, f0 + 2, f32m);
        bv[3] = ldf(b2, f0 + 3, f32m);
        #pragma unroll
        for (int et = 0; et < 4; et++) acc[ft][et] = bv;
    }
    #pragma unroll
    for (int ks = 0; ks < 4; ks++) {
        short8 a[2], bb[4];
        #pragma unroll
        for (int ft = 0; ft < 2; ft++)
            a[ft] = ((const short8*)W2p)[((w * 2 + ft) * 4 + ks) * 64 + lane];
        #pragma unroll
        for (int et = 0; et < 4; et++)
            bb[et] = *(const short8*)&zB[swz(et * 16 + cl, ks * 32 + quad * 8)];
        #pragma unroll
        for (int ft = 0; ft < 2; ft++)
            #pragma unroll
            for (int et = 0; et < 4; et++)
                acc[ft][et] = __builtin_amdgcn_mfma_f32_16x16x32_bf16(
                    a[ft], bb[et], acc[ft][et], 0, 0, 0);
    }
    // per-lane partial dot of relu(z2) with W3 over this lane's 8 feats
    float p[4] = {0.f, 0.f, 0.f, 0.f};
    #pragma unroll
    for (int ft = 0; ft < 2; ft++) {
        int f0 = w * 32 + ft * 16 + quad * 4;
        float w3v0 = ldf(W3, f0 + 0, f32m);
        float w3v1 = ldf(W3, f0 + 1, f32m);
        float w3v2 = ldf(W3, f0 + 2, f32m);
        float w3v3 = ldf(W3, f0 + 3, f32m);
        #pragma unroll
        for (int et = 0; et < 4; et++) {
            f32x4 v = acc[ft][et];
            p[et] = fmaf(fmaxf(v[0], 0.f), w3v0, p[et]);
            p[et] = fmaf(fmaxf(v[1], 0.f), w3v1, p[et]);
            p[et] = fmaf(fmaxf(v[2], 0.f), w3v2, p[et]);
            p[et] = fmaf(fmaxf(v[3], 0.f), w3v3, p[et]);
        }
    }
    // reduce over quads (lanes cl, cl+16, cl+32, cl+48)
    #pragma unroll
    for (int et = 0; et < 4; et++) {
        p[et] += __shfl_xor(p[et], 16);
        p[et] += __shfl_xor(p[et], 32);
    }
    if (lane < 16) {
        #pragma unroll
        for (int et = 0; et < 4; et++)
            psum[w * 64 + et * 16 + lane] = p[et];
    }
    __syncthreads();
    if (t < 64) {
        int eg = e0 + t;
        if (eg < ne) {
            float sum = ldf(b3, 0, f32m) + (psum[t] + psum[64 + t])
                      + (psum[128 + t] + psum[192 + t]);
            if (f32m) ((float*)out)[obase + eg] = sum;
            else      ((u16*)out)[obase + eg]   = f2bf(sum);
        }
    }
}

extern "C" void kernel_launch(void* const* d_in, const int* in_sizes, int n_in,
                              void* d_out, int out_size, void* d_ws, size_t ws_size,
                              hipStream_t stream) {
    const void* x      = d_in[0];
    const int* src     = (const int*)d_in[1];
    const int* dst     = (const int*)d_in[2];
    const int* pos_src = (const int*)d_in[3];
    const int* pos_dst = (const int*)d_in[4];
    const int* neg_src = (const int*)d_in[5];
    const int* neg_dst = (const int*)d_in[6];
    const void* Ws0 = d_in[7];
    const void* Wn0 = d_in[8];
    const void* b0  = d_in[9];
    const void* Ws1 = d_in[10];
    const void* Wn1 = d_in[11];
    const void* b1  = d_in[12];
    const void* dW1 = d_in[13];
    const void* db1 = d_in[14];
    const void* dW2 = d_in[15];
    const void* db2 = d_in[16];
    const void* dW3 = d_in[17];
    const void* db3 = d_in[18];

    const int n  = in_sizes[0] / HD;
    const int e  = in_sizes[1];
    const int ep = in_sizes[3];
    const int en = in_sizes[5];
    const int NB = (n + 255) / 256;
    const int PB = (ep + 63) / 64, NDB = (en + 63) / 64;

    // ws: aggb/h2[n*HD] u16 | h1[n*HD] u16 | mode | rowptr | cnt | cidx | bsum | packed W x6
    char* base = (char*)d_ws;
    u16* aggb = (u16*)d_ws;              // doubles as h2 (block-private rows)
    u16* h1   = aggb + (size_t)n * HD;
    size_t off = (size_t)n * HD * 4;     // two u16 planes
    int* mode = (int*)(base + off);      off += 16;
    int* rowptr = (int*)(base + off);    off += (size_t)(n + 1) * 4; off = (off + 15) & ~(size_t)15;
    int* cnt = (int*)(base + off);       off += (size_t)n * 4;       off = (off + 15) & ~(size_t)15;
    int* cidx = (int*)(base + off);      off += (size_t)e * 4;       off = (off + 15) & ~(size_t)15;
    int* bsum = (int*)(base + off);      off += (size_t)NB * 4;      off = (off + 15) & ~(size_t)15;
    u16* Wpk  = (u16*)(base + off);      // order: dW1, dW2, Ws0, Wn0, Ws1, Wn1
    u16* W1p  = Wpk;
    u16* W2p  = Wpk + 16384;
    u16* Ws0p = Wpk + 2 * 16384;
    u16* Wn0p = Wpk + 3 * 16384;
    u16* Ws1p = Wpk + 4 * 16384;
    u16* Wn1p = Wpk + 5 * 16384;

    detect_mode<<<dim3(1), dim3(256), 0, stream>>>((const u32*)x, mode);

    // ---- CSR build (once) ----
    hipMemsetAsync(cnt, 0, (size_t)n * 4, stream);
    cnt_count<<<dim3((e + 255) / 256), dim3(256), 0, stream>>>(dst, cnt, e);
    scan_blocks<<<dim3(NB), dim3(256), 0, stream>>>(cnt, rowptr, bsum, n);
    scan_bsum<<<dim3(1), dim3(1024), 0, stream>>>(bsum, NB);
    scan_add<<<dim3((n + 256) / 256), dim3(256), 0, stream>>>(rowptr, bsum, n, e);
    hipMemsetAsync(cnt, 0, (size_t)n * 4, stream);   // reuse as cursor
    csr_fill<<<dim3((e + 255) / 256), dim3(256), 0, stream>>>(src, dst, rowptr, cnt, cidx, e);

    pack_w6<<<dim3(384), dim3(256), 0, stream>>>(dW1, dW2, Ws0, Wn0, Ws1, Wn1, Wpk, mode);

    // ---- layer 0: h1 = relu(x@Ws0 + mean@Wn0 + b0) ----
    agg_gather<<<dim3((n * 64 + 255) / 256), dim3(256), 0, stream>>>(
        x, rowptr, cidx, aggb, mode, 1, n);
    sage_mfma<true><<<dim3((n + 63) / 64), dim3(256), 0, stream>>>(
        x, aggb, Ws0p, Wn0p, b0, h1, mode, 1, n);

    // ---- layer 1: h2 = h1@Ws1 + mean(h1)@Wn1 + b1  (h2 aliases aggb) ----
    agg_gather<<<dim3((n * 64 + 255) / 256), dim3(256), 0, stream>>>(
        h1, rowptr, cidx, aggb, mode, 0, n);
    sage_mfma<false><<<dim3((n + 63) / 64), dim3(256), 0, stream>>>(
        h1, aggb, Ws1p, Wn1p, b1, aggb /*h2 in-place*/, mode, 0, n);

    // ---- fused pos+neg decoder on h2 (bf16) ----
    edge_decode_mfma<<<dim3(PB + NDB), dim3(256), 0, stream>>>(
        aggb, pos_src, pos_dst, ep, PB, neg_src, neg_dst, en,
        W1p, db1, W2p, db2, dW3, db3, d_out, mode);
}